// Round 8
// baseline (432.110 us; speedup 1.0000x reference)
//
#include <hip/hip_runtime.h>
#include <math.h>

#define N_NODES 100000
#define N_EDGES 1600000
#define D_IN 256
#define D_H 128
#define D_OUT 32
#define N_PAD 102400
#define NB 196       // ceil(100000/512) buckets of 512 target nodes
#define CAPB 10240   // fixed capacity per bucket (mean 8163, +20 sigma)
#define CHUNK 4096   // edges per bucketA block

typedef long long ll;
typedef unsigned int uint;
typedef unsigned short ushort;
typedef short frag_ab __attribute__((ext_vector_type(8)));   // 8 bf16
typedef float frag_cd __attribute__((ext_vector_type(4)));   // 4 f32

__device__ __forceinline__ ushort f2bf(float f) {            // RNE fp32->bf16
    uint u = __float_as_uint(f);
    u += 0x7FFFu + ((u >> 16) & 1u);
    return (ushort)(u >> 16);
}
__device__ __forceinline__ float bfl(uint u) { return __uint_as_float(u << 16); }
__device__ __forceinline__ float bfh(uint u) { return __uint_as_float(u & 0xFFFF0000u); }
__device__ __forceinline__ uint packbf(float a, float b) {
    return (uint)f2bf(a) | ((uint)f2bf(b) << 16);
}

// ---- pass A: deg histogram + bucket partition (no per-thread arrays: re-read inputs)
//      + fused weight transpose/convert in the tail (independent work).
// pair = (row<<9) | (col&511); bucket = col>>9
__global__ __launch_bounds__(256) void k_bucketA(const int* __restrict__ row,
                                                 const int* __restrict__ col,
                                                 int* __restrict__ deg,
                                                 int* __restrict__ gcur,
                                                 uint* __restrict__ pairs,
                                                 const float* __restrict__ W1,
                                                 const float* __restrict__ W2,
                                                 ushort* __restrict__ w1t,
                                                 ushort* __restrict__ w2t, int e) {
    __shared__ int cnt[NB];
    __shared__ int lst[NB];
    const int t = threadIdx.x;
    for (int i = t; i < NB; i += 256) cnt[i] = 0;
    __syncthreads();
    const int base = blockIdx.x * CHUNK;
    const int end = min(base + CHUNK, e);
    for (int idx = base + t; idx < end; idx += 256) {
        int c = col[idx];
        atomicAdd(&deg[c], 1);
        atomicAdd(&cnt[c >> 9], 1);
    }
    __syncthreads();
    for (int i = t; i < NB; i += 256) {
        int c = cnt[i];
        lst[i] = (c > 0) ? atomicAdd(&gcur[i], c) : 0;
        cnt[i] = 0;  // reuse as local cursor
    }
    __syncthreads();
    for (int idx = base + t; idx < end; idx += 256) {  // re-read (L2-hot)
        int c = col[idx], r = row[idx];
        int b = c >> 9;
        int rel = lst[b] + atomicAdd(&cnt[b], 1);
        if (rel < CAPB) pairs[b * CAPB + rel] = ((uint)r << 9) | (uint)(c & 511);
    }
    // fused prep_w (flat over grid; 391*256 threads cover 36864 elements)
    int gi = blockIdx.x * 256 + t;
    if (gi < D_IN * D_H) {
        int k = gi >> 7, nn = gi & 127;
        w1t[nn * D_IN + k] = f2bf(W1[gi]);
    } else if (gi < D_IN * D_H + D_H * D_OUT) {
        int j = gi - D_IN * D_H;
        int k = j >> 5, nn = j & 31;
        w2t[nn * D_H + k] = f2bf(W2[j]);
    }
}

// ---- fused fill: per-bucket LDS scan of deg -> rp (padded CSR at b*CAPB), dinv,
//      then scatter fill. 4 blocks per bucket share global off[] cursors.
__global__ __launch_bounds__(256) void k_fill2(const uint* __restrict__ pairs,
                                               const int* __restrict__ gcur,
                                               const int* __restrict__ deg,
                                               int* __restrict__ rp,
                                               float* __restrict__ dinv,
                                               int* __restrict__ off,
                                               int* __restrict__ csr_src, int n) {
    __shared__ int ssum[256];
    __shared__ int rps[512];
    const int b = blockIdx.x >> 2, p = blockIdx.x & 3, t = threadIdx.x;
    const int node0 = b << 9;
    int d0 = deg[node0 + 2 * t];       // deg zeroed beyond n, N_PAD covers 100352
    int d1 = deg[node0 + 2 * t + 1];
    ssum[t] = d0 + d1;
    __syncthreads();
    for (int o = 1; o < 256; o <<= 1) {
        int v = (t >= o) ? ssum[t - o] : 0;
        __syncthreads();
        ssum[t] += v;
        __syncthreads();
    }
    int excl = ssum[t] - (d0 + d1);
    rps[2 * t]     = b * CAPB + excl;
    rps[2 * t + 1] = b * CAPB + excl + d0;
    __syncthreads();
    if (p == 0) {
        for (int i = t; i < 512; i += 256) {
            int v = node0 + i;
            if (v < n) {
                rp[v] = rps[i];
                dinv[v] = rsqrtf((float)(1 + deg[v]));
            }
        }
    }
    const int cnt = min(gcur[b], CAPB);
    const int chunk = (cnt + 3) >> 2;
    const int s = p * chunk, en = min(s + chunk, cnt);
    const uint* pr = pairs + b * CAPB;
    for (int i = s + t; i < en; i += 256) {
        uint pp = pr[i];
        int loc = (int)(pp & 511);
        int pos = rps[loc] + atomicAdd(&off[node0 + loc], 1);
        csr_src[pos] = (int)(pp >> 9);
    }
}

// ---------------- GEMM1 (MFMA, LDS-free): hxs = bf16( dinv * (x @ W1) ) ----------------
__global__ __launch_bounds__(256, 3) void k_gemm1(const float* __restrict__ x,
                                                  const ushort* __restrict__ w1t,
                                                  const float* __restrict__ dinv,
                                                  ushort* __restrict__ hxs, int n) {
    const int tid = threadIdx.x;
    const int wv = tid >> 6, lane = tid & 63;
    const int lm = lane & 15, quad = lane >> 4;
    const int base = blockIdx.x * 128 + wv * 32;

    frag_cd acc[2][8];
#pragma unroll
    for (int mt = 0; mt < 2; mt++)
#pragma unroll
        for (int nt = 0; nt < 8; nt++) acc[mt][nt] = (frag_cd){0.f, 0.f, 0.f, 0.f};

    const float4* xr[2];
#pragma unroll
    for (int mt = 0; mt < 2; mt++) {
        int node = base + mt * 16 + lm;
        xr[mt] = (const float4*)(x + (ll)min(node, n - 1) * D_IN);
    }

#pragma unroll
    for (int ks = 0; ks < 8; ks++) {
        frag_ab a[2];
#pragma unroll
        for (int mt = 0; mt < 2; mt++) {
            float4 v0 = xr[mt][ks * 8 + quad * 2];
            float4 v1 = xr[mt][ks * 8 + quad * 2 + 1];
            uint* ap = (uint*)&a[mt];
            ap[0] = packbf(v0.x, v0.y);
            ap[1] = packbf(v0.z, v0.w);
            ap[2] = packbf(v1.x, v1.y);
            ap[3] = packbf(v1.z, v1.w);
        }
#pragma unroll
        for (int nt = 0; nt < 8; nt++) {
            frag_ab b = *(const frag_ab*)&w1t[(nt * 16 + lm) * D_IN + ks * 32 + quad * 8];
#pragma unroll
            for (int mt = 0; mt < 2; mt++)
                acc[mt][nt] = __builtin_amdgcn_mfma_f32_16x16x32_bf16(
                    a[mt], b, acc[mt][nt], 0, 0, 0);
        }
    }

#pragma unroll
    for (int mt = 0; mt < 2; mt++) {
#pragma unroll
        for (int r = 0; r < 4; r++) {
            int node = base + mt * 16 + quad * 4 + r;
            if (node < n) {
                float dv = dinv[node];
#pragma unroll
                for (int nt = 0; nt < 8; nt++)
                    hxs[(ll)node * D_H + nt * 16 + lm] = f2bf(acc[mt][nt][r] * dv);
            }
        }
    }
}

// ---------------- layer-1 gather (bf16 rows): one wave per node ----------------
__global__ __launch_bounds__(256) void k_agg1(const uint* __restrict__ hxs,
                                              const int* __restrict__ csr_src,
                                              const int* __restrict__ rp,
                                              const int* __restrict__ deg,
                                              const float* __restrict__ dinv,
                                              const float* __restrict__ b1,
                                              uint* __restrict__ h, int n) {
    int v = blockIdx.x * 4 + (threadIdx.x >> 6);
    if (v >= n) return;
    int lane = threadIdx.x & 63;
    uint u = hxs[v * 64 + lane];
    float a0 = bfl(u), a1 = bfh(u);
    int s = rp[v], e = s + deg[v];
    int i = s;
    for (; i + 7 < e; i += 8) {
        int s0 = csr_src[i], s1 = csr_src[i + 1];
        int s2 = csr_src[i + 2], s3 = csr_src[i + 3];
        int s4 = csr_src[i + 4], s5 = csr_src[i + 5];
        int s6 = csr_src[i + 6], s7 = csr_src[i + 7];
        uint u0 = hxs[s0 * 64 + lane], u1 = hxs[s1 * 64 + lane];
        uint u2 = hxs[s2 * 64 + lane], u3 = hxs[s3 * 64 + lane];
        uint u4 = hxs[s4 * 64 + lane], u5 = hxs[s5 * 64 + lane];
        uint u6 = hxs[s6 * 64 + lane], u7 = hxs[s7 * 64 + lane];
        a0 += bfl(u0) + bfl(u1) + bfl(u2) + bfl(u3) + bfl(u4) + bfl(u5) + bfl(u6) + bfl(u7);
        a1 += bfh(u0) + bfh(u1) + bfh(u2) + bfh(u3) + bfh(u4) + bfh(u5) + bfh(u6) + bfh(u7);
    }
    for (; i + 1 < e; i += 2) {
        int s0 = csr_src[i], s1 = csr_src[i + 1];
        uint u0 = hxs[s0 * 64 + lane], u1 = hxs[s1 * 64 + lane];
        a0 += bfl(u0) + bfl(u1);
        a1 += bfh(u0) + bfh(u1);
    }
    if (i < e) {
        uint u0 = hxs[csr_src[i] * 64 + lane];
        a0 += bfl(u0);
        a1 += bfh(u0);
    }
    float dv = dinv[v];
    float2 bb = ((const float2*)b1)[lane];
    h[v * 64 + lane] = packbf(fmaxf(fmaf(dv, a0, bb.x), 0.f),
                              fmaxf(fmaf(dv, a1, bb.y), 0.f));
}

// ---------------- GEMM2 (MFMA, LDS-free): hx2s = bf16( dinv * (h @ W2) ) ----------------
__global__ __launch_bounds__(256) void k_gemm2(const ushort* __restrict__ h,
                                               const ushort* __restrict__ w2t,
                                               const float* __restrict__ dinv,
                                               ushort* __restrict__ hx2s, int n) {
    const int tid = threadIdx.x;
    const int wv = tid >> 6, lane = tid & 63;
    const int lm = lane & 15, quad = lane >> 4;
    const int base = blockIdx.x * 128 + wv * 32;

    frag_cd acc[2][2];
#pragma unroll
    for (int mt = 0; mt < 2; mt++)
#pragma unroll
        for (int nt = 0; nt < 2; nt++) acc[mt][nt] = (frag_cd){0.f, 0.f, 0.f, 0.f};

    const ushort* hr[2];
#pragma unroll
    for (int mt = 0; mt < 2; mt++) {
        int node = base + mt * 16 + lm;
        hr[mt] = h + (ll)min(node, n - 1) * D_H;
    }

#pragma unroll
    for (int ks = 0; ks < 4; ks++) {
        frag_ab a[2], b[2];
#pragma unroll
        for (int mt = 0; mt < 2; mt++)
            a[mt] = *(const frag_ab*)&hr[mt][ks * 32 + quad * 8];
#pragma unroll
        for (int nt = 0; nt < 2; nt++)
            b[nt] = *(const frag_ab*)&w2t[(nt * 16 + lm) * D_H + ks * 32 + quad * 8];
#pragma unroll
        for (int mt = 0; mt < 2; mt++)
#pragma unroll
            for (int nt = 0; nt < 2; nt++)
                acc[mt][nt] = __builtin_amdgcn_mfma_f32_16x16x32_bf16(
                    a[mt], b[nt], acc[mt][nt], 0, 0, 0);
    }

#pragma unroll
    for (int mt = 0; mt < 2; mt++) {
#pragma unroll
        for (int r = 0; r < 4; r++) {
            int node = base + mt * 16 + quad * 4 + r;
            if (node < n) {
                float dv = dinv[node];
#pragma unroll
                for (int nt = 0; nt < 2; nt++)
                    hx2s[(ll)node * D_OUT + nt * 16 + lm] = f2bf(acc[mt][nt][r] * dv);
            }
        }
    }
}

// ---------------- layer-2 gather + bias + log_softmax: 16 lanes per node ----------------
__global__ __launch_bounds__(256) void k_agg2(const uint* __restrict__ hx2s,
                                              const int* __restrict__ csr_src,
                                              const int* __restrict__ rp,
                                              const int* __restrict__ deg,
                                              const float* __restrict__ dinv,
                                              const float* __restrict__ b2,
                                              float2* __restrict__ out, int n) {
    int v = blockIdx.x * 16 + (threadIdx.x >> 4);
    if (v >= n) return;
    int l16 = threadIdx.x & 15;
    uint u = hx2s[v * 16 + l16];
    float a0 = bfl(u), a1 = bfh(u);
    int s = rp[v], e = s + deg[v];
    int i = s;
    for (; i + 7 < e; i += 8) {
        int s0 = csr_src[i], s1 = csr_src[i + 1];
        int s2 = csr_src[i + 2], s3 = csr_src[i + 3];
        int s4 = csr_src[i + 4], s5 = csr_src[i + 5];
        int s6 = csr_src[i + 6], s7 = csr_src[i + 7];
        uint u0 = hx2s[s0 * 16 + l16], u1 = hx2s[s1 * 16 + l16];
        uint u2 = hx2s[s2 * 16 + l16], u3 = hx2s[s3 * 16 + l16];
        uint u4 = hx2s[s4 * 16 + l16], u5 = hx2s[s5 * 16 + l16];
        uint u6 = hx2s[s6 * 16 + l16], u7 = hx2s[s7 * 16 + l16];
        a0 += bfl(u0) + bfl(u1) + bfl(u2) + bfl(u3) + bfl(u4) + bfl(u5) + bfl(u6) + bfl(u7);
        a1 += bfh(u0) + bfh(u1) + bfh(u2) + bfh(u3) + bfh(u4) + bfh(u5) + bfh(u6) + bfh(u7);
    }
    for (; i + 1 < e; i += 2) {
        int s0 = csr_src[i], s1 = csr_src[i + 1];
        uint u0 = hx2s[s0 * 16 + l16], u1 = hx2s[s1 * 16 + l16];
        a0 += bfl(u0) + bfl(u1);
        a1 += bfh(u0) + bfh(u1);
    }
    if (i < e) {
        uint u0 = hx2s[csr_src[i] * 16 + l16];
        a0 += bfl(u0);
        a1 += bfh(u0);
    }
    float dv = dinv[v];
    float2 bb = ((const float2*)b2)[l16];
    float t0 = fmaf(dv, a0, bb.x), t1 = fmaf(dv, a1, bb.y);
    float mx = fmaxf(t0, t1);
#pragma unroll
    for (int m = 8; m >= 1; m >>= 1) mx = fmaxf(mx, __shfl_xor(mx, m));
    float sum = __expf(t0 - mx) + __expf(t1 - mx);
#pragma unroll
    for (int m = 8; m >= 1; m >>= 1) sum += __shfl_xor(sum, m);
    float lse = mx + __logf(sum);
    out[v * 16 + l16] = make_float2(t0 - lse, t1 - lse);
}

extern "C" void kernel_launch(void* const* d_in, const int* in_sizes, int n_in,
                              void* d_out, int out_size, void* d_ws, size_t ws_size,
                              hipStream_t stream) {
    const float* x  = (const float*)d_in[0];
    const float* W1 = (const float*)d_in[1];
    const float* b1 = (const float*)d_in[2];
    const float* W2 = (const float*)d_in[3];
    const float* b2 = (const float*)d_in[4];
    const int*   ei = (const int*)d_in[5];
    const int* row = ei;
    const int* col = ei + N_EDGES;

    // ws layout (4B words): deg[N_PAD] | gcur[256] | off[N_PAD] | rp[N_PAD] | dinv[N_PAD] |
    //   csr_src[NB*CAPB] | pairs[NB*CAPB] | w1t | w2t | hxs | h | hx2s   (~68 MB)
    int*    ws_i    = (int*)d_ws;
    int*    deg     = ws_i;
    int*    gcur    = ws_i + N_PAD;
    int*    off     = ws_i + N_PAD + 256;
    int*    rp      = ws_i + 2 * N_PAD + 256;
    float*  dinv    = (float*)(ws_i + 3 * N_PAD + 256);
    int*    csr_src = ws_i + 4 * N_PAD + 256;
    uint*   pairs   = (uint*)(csr_src + NB * CAPB);
    ushort* w1t     = (ushort*)(pairs + NB * CAPB);
    ushort* w2t     = w1t + D_IN * D_H;
    ushort* hxs     = w2t + D_H * D_OUT;
    ushort* h       = hxs + (ll)N_NODES * D_H;
    ushort* hx2s    = h + (ll)N_NODES * D_H;

    const int n = N_NODES, e = N_EDGES;

    hipMemsetAsync(deg, 0, (2 * N_PAD + 256) * sizeof(int), stream);  // deg | gcur | off
    k_bucketA<<<(e + CHUNK - 1) / CHUNK, 256, 0, stream>>>(row, col, deg, gcur, pairs,
                                                           W1, W2, w1t, w2t, e);
    k_fill2<<<NB * 4, 256, 0, stream>>>(pairs, gcur, deg, rp, dinv, off, csr_src, n);

    k_gemm1<<<(n + 127) / 128, 256, 0, stream>>>(x, w1t, dinv, hxs, n);
    k_agg1<<<(n + 3) / 4, 256, 0, stream>>>((const uint*)hxs, csr_src, rp, deg, dinv, b1,
                                            (uint*)h, n);
    k_gemm2<<<(n + 127) / 128, 256, 0, stream>>>(h, w2t, dinv, hx2s, n);
    k_agg2<<<(n + 15) / 16, 256, 0, stream>>>((const uint*)hx2s, csr_src, rp, deg, dinv, b2,
                                              (float2*)d_out, n);
}

// Round 9
// 397.710 us; speedup vs baseline: 1.0865x; 1.0865x over previous
//
#include <hip/hip_runtime.h>
#include <math.h>

#define N_NODES 100000
#define N_EDGES 1600000
#define D_IN 256
#define D_H 128
#define D_OUT 32
#define N_PAD 102400
#define NB 196       // ceil(100000/512) buckets of 512 target nodes
#define CAPB 10240   // fixed capacity per bucket (mean 8163, +23 sigma)
#define CHUNK 2048   // edges per bucketA block -> 782 blocks

typedef long long ll;
typedef unsigned int uint;
typedef unsigned short ushort;
typedef unsigned char uchar;
typedef short frag_ab __attribute__((ext_vector_type(8)));   // 8 bf16
typedef float frag_cd __attribute__((ext_vector_type(4)));   // 4 f32

__device__ __forceinline__ ushort f2bf(float f) {            // RNE fp32->bf16
    uint u = __float_as_uint(f);
    u += 0x7FFFu + ((u >> 16) & 1u);
    return (ushort)(u >> 16);
}
__device__ __forceinline__ float bfl(uint u) { return __uint_as_float(u << 16); }
__device__ __forceinline__ float bfh(uint u) { return __uint_as_float(u & 0xFFFF0000u); }
__device__ __forceinline__ uint packbf(float a, float b) {
    return (uint)f2bf(a) | ((uint)f2bf(b) << 16);
}

// ---- pass A: deg histogram + bucket partition with LDS-sorted staged emission.
// pair = (row<<9) | (col&511); bucket = col>>9. Fused prep_w tail.
__global__ __launch_bounds__(256) void k_bucketA(const int* __restrict__ row,
                                                 const int* __restrict__ col,
                                                 int* __restrict__ deg,
                                                 int* __restrict__ gcur,
                                                 uint* __restrict__ pairs,
                                                 const float* __restrict__ W1,
                                                 const float* __restrict__ W2,
                                                 ushort* __restrict__ w1t,
                                                 ushort* __restrict__ w2t, int e) {
    __shared__ int cnt[NB];      // counts, then phase-2 cursors
    __shared__ int lofs[NB];     // local sorted offsets
    __shared__ int lstart[NB];   // claimed global run starts
    __shared__ int sc[256];      // scan temp
    __shared__ uint spair[CHUNK];
    __shared__ uchar sbuck[CHUNK];
    const int t = threadIdx.x;
    for (int i = t; i < NB; i += 256) cnt[i] = 0;
    __syncthreads();
    const int base = blockIdx.x * CHUNK;
    const int end = min(base + CHUNK, e);
    const int valid = end - base;
    for (int idx = base + t; idx < end; idx += 256) {
        int c = col[idx];
        atomicAdd(&deg[c], 1);
        atomicAdd(&cnt[c >> 9], 1);
    }
    __syncthreads();
    int v = (t < NB) ? cnt[t] : 0;
    sc[t] = v;
    __syncthreads();
    for (int o = 1; o < 256; o <<= 1) {
        int u2 = (t >= o) ? sc[t - o] : 0;
        __syncthreads();
        sc[t] += u2;
        __syncthreads();
    }
    if (t < NB) {
        lofs[t] = sc[t] - v;
        lstart[t] = (v > 0) ? atomicAdd(&gcur[t], v) : 0;
        cnt[t] = 0;  // reuse as local cursor
    }
    __syncthreads();
    for (int idx = base + t; idx < end; idx += 256) {   // re-read (L2-hot)
        int c = col[idx], r = row[idx];
        int b = c >> 9;
        int pos = lofs[b] + atomicAdd(&cnt[b], 1);
        spair[pos] = ((uint)r << 9) | (uint)(c & 511);
        sbuck[pos] = (uchar)b;
    }
    __syncthreads();
    for (int i = t; i < valid; i += 256) {              // bucket-contiguous emission
        int b = sbuck[i];
        int rel = lstart[b] + (i - lofs[b]);
        if (rel < CAPB) pairs[b * CAPB + rel] = spair[i];
    }
    // fused prep_w (first 144 blocks cover 36864 elements)
    int gi = blockIdx.x * 256 + t;
    if (gi < D_IN * D_H) {
        int k = gi >> 7, nn = gi & 127;
        w1t[nn * D_IN + k] = f2bf(W1[gi]);
    } else if (gi < D_IN * D_H + D_H * D_OUT) {
        int j = gi - D_IN * D_H;
        int k = j >> 5, nn = j & 31;
        w2t[nn * D_H + k] = f2bf(W2[j]);
    }
}

// ---- pass B: one block per bucket; LDS-staged CSR fill (coalesced global write),
//      plus rp (padded CSR base) and dinv.
__global__ __launch_bounds__(256) void k_fillB(const uint* __restrict__ pairs,
                                               const int* __restrict__ gcur,
                                               const int* __restrict__ deg,
                                               int* __restrict__ rp,
                                               float* __restrict__ dinv,
                                               int* __restrict__ csr_src, int n) {
    __shared__ int scsr[CAPB];   // 40 KB staged csr for this bucket
    __shared__ int lrp[512];     // bucket-relative row starts
    __shared__ int cur[512];     // scatter cursors
    __shared__ int ssum[256];
    const int b = blockIdx.x, t = threadIdx.x;
    const int node0 = b << 9;
    int d0 = deg[node0 + 2 * t];         // deg zeroed beyond n (N_PAD covers 100352)
    int d1 = deg[node0 + 2 * t + 1];
    ssum[t] = d0 + d1;
    __syncthreads();
    for (int o = 1; o < 256; o <<= 1) {
        int u2 = (t >= o) ? ssum[t - o] : 0;
        __syncthreads();
        ssum[t] += u2;
        __syncthreads();
    }
    int excl = ssum[t] - (d0 + d1);
    lrp[2 * t] = excl;
    lrp[2 * t + 1] = excl + d0;
    cur[2 * t] = excl;
    cur[2 * t + 1] = excl + d0;
    __syncthreads();
    for (int i = t; i < 512; i += 256) {
        int vv = node0 + i;
        if (vv < n) {
            rp[vv] = b * CAPB + lrp[i];
            dinv[vv] = rsqrtf((float)(1 + deg[vv]));
        }
    }
    const int cnt = min(gcur[b], CAPB);
    const uint* pr = pairs + b * CAPB;
    for (int i = t; i < cnt; i += 256) {
        uint pp = pr[i];
        int pos = atomicAdd(&cur[pp & 511], 1);
        if (pos < CAPB) scsr[pos] = (int)(pp >> 9);
    }
    __syncthreads();
    for (int i = t; i < cnt; i += 256)   // coalesced contiguous write
        csr_src[b * CAPB + i] = scsr[i];
}

// ---------------- GEMM1 (MFMA, LDS-free): hxs = bf16( dinv * (x @ W1) ) ----------------
__global__ __launch_bounds__(256, 3) void k_gemm1(const float* __restrict__ x,
                                                  const ushort* __restrict__ w1t,
                                                  const float* __restrict__ dinv,
                                                  ushort* __restrict__ hxs, int n) {
    const int tid = threadIdx.x;
    const int wv = tid >> 6, lane = tid & 63;
    const int lm = lane & 15, quad = lane >> 4;
    const int base = blockIdx.x * 128 + wv * 32;

    frag_cd acc[2][8];
#pragma unroll
    for (int mt = 0; mt < 2; mt++)
#pragma unroll
        for (int nt = 0; nt < 8; nt++) acc[mt][nt] = (frag_cd){0.f, 0.f, 0.f, 0.f};

    const float4* xr[2];
#pragma unroll
    for (int mt = 0; mt < 2; mt++) {
        int node = base + mt * 16 + lm;
        xr[mt] = (const float4*)(x + (ll)min(node, n - 1) * D_IN);
    }

#pragma unroll
    for (int ks = 0; ks < 8; ks++) {
        frag_ab a[2];
#pragma unroll
        for (int mt = 0; mt < 2; mt++) {
            float4 v0 = xr[mt][ks * 8 + quad * 2];
            float4 v1 = xr[mt][ks * 8 + quad * 2 + 1];
            uint* ap = (uint*)&a[mt];
            ap[0] = packbf(v0.x, v0.y);
            ap[1] = packbf(v0.z, v0.w);
            ap[2] = packbf(v1.x, v1.y);
            ap[3] = packbf(v1.z, v1.w);
        }
#pragma unroll
        for (int nt = 0; nt < 8; nt++) {
            frag_ab b = *(const frag_ab*)&w1t[(nt * 16 + lm) * D_IN + ks * 32 + quad * 8];
#pragma unroll
            for (int mt = 0; mt < 2; mt++)
                acc[mt][nt] = __builtin_amdgcn_mfma_f32_16x16x32_bf16(
                    a[mt], b, acc[mt][nt], 0, 0, 0);
        }
    }

#pragma unroll
    for (int mt = 0; mt < 2; mt++) {
#pragma unroll
        for (int r = 0; r < 4; r++) {
            int node = base + mt * 16 + quad * 4 + r;
            if (node < n) {
                float dv = dinv[node];
#pragma unroll
                for (int nt = 0; nt < 8; nt++)
                    hxs[(ll)node * D_H + nt * 16 + lm] = f2bf(acc[mt][nt][r] * dv);
            }
        }
    }
}

// ---------------- layer-1 gather (bf16 rows): one wave per node ----------------
__global__ __launch_bounds__(256) void k_agg1(const uint* __restrict__ hxs,
                                              const int* __restrict__ csr_src,
                                              const int* __restrict__ rp,
                                              const int* __restrict__ deg,
                                              const float* __restrict__ dinv,
                                              const float* __restrict__ b1,
                                              uint* __restrict__ h, int n) {
    int v = blockIdx.x * 4 + (threadIdx.x >> 6);
    if (v >= n) return;
    int lane = threadIdx.x & 63;
    uint u = hxs[v * 64 + lane];
    float a0 = bfl(u), a1 = bfh(u);
    int s = rp[v], e = s + deg[v];
    int i = s;
    for (; i + 7 < e; i += 8) {
        int s0 = csr_src[i], s1 = csr_src[i + 1];
        int s2 = csr_src[i + 2], s3 = csr_src[i + 3];
        int s4 = csr_src[i + 4], s5 = csr_src[i + 5];
        int s6 = csr_src[i + 6], s7 = csr_src[i + 7];
        uint u0 = hxs[s0 * 64 + lane], u1 = hxs[s1 * 64 + lane];
        uint u2 = hxs[s2 * 64 + lane], u3 = hxs[s3 * 64 + lane];
        uint u4 = hxs[s4 * 64 + lane], u5 = hxs[s5 * 64 + lane];
        uint u6 = hxs[s6 * 64 + lane], u7 = hxs[s7 * 64 + lane];
        a0 += bfl(u0) + bfl(u1) + bfl(u2) + bfl(u3) + bfl(u4) + bfl(u5) + bfl(u6) + bfl(u7);
        a1 += bfh(u0) + bfh(u1) + bfh(u2) + bfh(u3) + bfh(u4) + bfh(u5) + bfh(u6) + bfh(u7);
    }
    for (; i + 1 < e; i += 2) {
        int s0 = csr_src[i], s1 = csr_src[i + 1];
        uint u0 = hxs[s0 * 64 + lane], u1 = hxs[s1 * 64 + lane];
        a0 += bfl(u0) + bfl(u1);
        a1 += bfh(u0) + bfh(u1);
    }
    if (i < e) {
        uint u0 = hxs[csr_src[i] * 64 + lane];
        a0 += bfl(u0);
        a1 += bfh(u0);
    }
    float dv = dinv[v];
    float2 bb = ((const float2*)b1)[lane];
    h[v * 64 + lane] = packbf(fmaxf(fmaf(dv, a0, bb.x), 0.f),
                              fmaxf(fmaf(dv, a1, bb.y), 0.f));
}

// ---------------- GEMM2 (MFMA, LDS-free): hx2s = bf16( dinv * (h @ W2) ) ----------------
__global__ __launch_bounds__(256) void k_gemm2(const ushort* __restrict__ h,
                                               const ushort* __restrict__ w2t,
                                               const float* __restrict__ dinv,
                                               ushort* __restrict__ hx2s, int n) {
    const int tid = threadIdx.x;
    const int wv = tid >> 6, lane = tid & 63;
    const int lm = lane & 15, quad = lane >> 4;
    const int base = blockIdx.x * 128 + wv * 32;

    frag_cd acc[2][2];
#pragma unroll
    for (int mt = 0; mt < 2; mt++)
#pragma unroll
        for (int nt = 0; nt < 2; nt++) acc[mt][nt] = (frag_cd){0.f, 0.f, 0.f, 0.f};

    const ushort* hr[2];
#pragma unroll
    for (int mt = 0; mt < 2; mt++) {
        int node = base + mt * 16 + lm;
        hr[mt] = h + (ll)min(node, n - 1) * D_H;
    }

#pragma unroll
    for (int ks = 0; ks < 4; ks++) {
        frag_ab a[2], b[2];
#pragma unroll
        for (int mt = 0; mt < 2; mt++)
            a[mt] = *(const frag_ab*)&hr[mt][ks * 32 + quad * 8];
#pragma unroll
        for (int nt = 0; nt < 2; nt++)
            b[nt] = *(const frag_ab*)&w2t[(nt * 16 + lm) * D_H + ks * 32 + quad * 8];
#pragma unroll
        for (int mt = 0; mt < 2; mt++)
#pragma unroll
            for (int nt = 0; nt < 2; nt++)
                acc[mt][nt] = __builtin_amdgcn_mfma_f32_16x16x32_bf16(
                    a[mt], b[nt], acc[mt][nt], 0, 0, 0);
    }

#pragma unroll
    for (int mt = 0; mt < 2; mt++) {
#pragma unroll
        for (int r = 0; r < 4; r++) {
            int node = base + mt * 16 + quad * 4 + r;
            if (node < n) {
                float dv = dinv[node];
#pragma unroll
                for (int nt = 0; nt < 2; nt++)
                    hx2s[(ll)node * D_OUT + nt * 16 + lm] = f2bf(acc[mt][nt][r] * dv);
            }
        }
    }
}

// ---------------- layer-2 gather + bias + log_softmax: 16 lanes per node ----------------
__global__ __launch_bounds__(256) void k_agg2(const uint* __restrict__ hx2s,
                                              const int* __restrict__ csr_src,
                                              const int* __restrict__ rp,
                                              const int* __restrict__ deg,
                                              const float* __restrict__ dinv,
                                              const float* __restrict__ b2,
                                              float2* __restrict__ out, int n) {
    int v = blockIdx.x * 16 + (threadIdx.x >> 4);
    if (v >= n) return;
    int l16 = threadIdx.x & 15;
    uint u = hx2s[v * 16 + l16];
    float a0 = bfl(u), a1 = bfh(u);
    int s = rp[v], e = s + deg[v];
    int i = s;
    for (; i + 7 < e; i += 8) {
        int s0 = csr_src[i], s1 = csr_src[i + 1];
        int s2 = csr_src[i + 2], s3 = csr_src[i + 3];
        int s4 = csr_src[i + 4], s5 = csr_src[i + 5];
        int s6 = csr_src[i + 6], s7 = csr_src[i + 7];
        uint u0 = hx2s[s0 * 16 + l16], u1 = hx2s[s1 * 16 + l16];
        uint u2 = hx2s[s2 * 16 + l16], u3 = hx2s[s3 * 16 + l16];
        uint u4 = hx2s[s4 * 16 + l16], u5 = hx2s[s5 * 16 + l16];
        uint u6 = hx2s[s6 * 16 + l16], u7 = hx2s[s7 * 16 + l16];
        a0 += bfl(u0) + bfl(u1) + bfl(u2) + bfl(u3) + bfl(u4) + bfl(u5) + bfl(u6) + bfl(u7);
        a1 += bfh(u0) + bfh(u1) + bfh(u2) + bfh(u3) + bfh(u4) + bfh(u5) + bfh(u6) + bfh(u7);
    }
    for (; i + 1 < e; i += 2) {
        int s0 = csr_src[i], s1 = csr_src[i + 1];
        uint u0 = hx2s[s0 * 16 + l16], u1 = hx2s[s1 * 16 + l16];
        a0 += bfl(u0) + bfl(u1);
        a1 += bfh(u0) + bfh(u1);
    }
    if (i < e) {
        uint u0 = hx2s[csr_src[i] * 16 + l16];
        a0 += bfl(u0);
        a1 += bfh(u0);
    }
    float dv = dinv[v];
    float2 bb = ((const float2*)b2)[l16];
    float t0 = fmaf(dv, a0, bb.x), t1 = fmaf(dv, a1, bb.y);
    float mx = fmaxf(t0, t1);
#pragma unroll
    for (int m = 8; m >= 1; m >>= 1) mx = fmaxf(mx, __shfl_xor(mx, m));
    float sum = __expf(t0 - mx) + __expf(t1 - mx);
#pragma unroll
    for (int m = 8; m >= 1; m >>= 1) sum += __shfl_xor(sum, m);
    float lse = mx + __logf(sum);
    out[v * 16 + l16] = make_float2(t0 - lse, t1 - lse);
}

extern "C" void kernel_launch(void* const* d_in, const int* in_sizes, int n_in,
                              void* d_out, int out_size, void* d_ws, size_t ws_size,
                              hipStream_t stream) {
    const float* x  = (const float*)d_in[0];
    const float* W1 = (const float*)d_in[1];
    const float* b1 = (const float*)d_in[2];
    const float* W2 = (const float*)d_in[3];
    const float* b2 = (const float*)d_in[4];
    const int*   ei = (const int*)d_in[5];
    const int* row = ei;
    const int* col = ei + N_EDGES;

    // ws layout (4B words): deg[N_PAD] | gcur[256] | rp[N_PAD] | dinv[N_PAD] |
    //   csr_src[NB*CAPB] | pairs[NB*CAPB] | w1t | w2t | hxs | h | hx2s
    int*    ws_i    = (int*)d_ws;
    int*    deg     = ws_i;
    int*    gcur    = ws_i + N_PAD;
    int*    rp      = ws_i + N_PAD + 256;
    float*  dinv    = (float*)(ws_i + 2 * N_PAD + 256);
    int*    csr_src = ws_i + 3 * N_PAD + 256;
    uint*   pairs   = (uint*)(csr_src + NB * CAPB);
    ushort* w1t     = (ushort*)(pairs + NB * CAPB);
    ushort* w2t     = w1t + D_IN * D_H;
    ushort* hxs     = w2t + D_H * D_OUT;
    ushort* h       = hxs + (ll)N_NODES * D_H;
    ushort* hx2s    = h + (ll)N_NODES * D_H;

    const int n = N_NODES, e = N_EDGES;

    hipMemsetAsync(deg, 0, (N_PAD + 256) * sizeof(int), stream);  // deg | gcur
    k_bucketA<<<(e + CHUNK - 1) / CHUNK, 256, 0, stream>>>(row, col, deg, gcur, pairs,
                                                           W1, W2, w1t, w2t, e);
    k_fillB<<<NB, 256, 0, stream>>>(pairs, gcur, deg, rp, dinv, csr_src, n);

    k_gemm1<<<(n + 127) / 128, 256, 0, stream>>>(x, w1t, dinv, hxs, n);
    k_agg1<<<(n + 3) / 4, 256, 0, stream>>>((const uint*)hxs, csr_src, rp, deg, dinv, b1,
                                            (uint*)h, n);
    k_gemm2<<<(n + 127) / 128, 256, 0, stream>>>(h, w2t, dinv, hx2s, n);
    k_agg2<<<(n + 15) / 16, 256, 0, stream>>>((const uint*)hx2s, csr_src, rp, deg, dinv, b2,
                                              (float2*)d_out, n);
}